// Round 13
// baseline (85.042 us; speedup 1.0000x reference)
//
#include <hip/hip_runtime.h>
#include <hip/hip_bf16.h>

using u16 = unsigned short;
using u32 = unsigned int;
typedef float f32x4 __attribute__((ext_vector_type(4)));
typedef float f32x2 __attribute__((ext_vector_type(2)));
typedef __bf16 bf16x8 __attribute__((ext_vector_type(8)));

// ---- helpers ----------------------------------------------------------------
static __device__ __forceinline__ float bflo(u32 u) { return __uint_as_float(u << 16); }
static __device__ __forceinline__ float bfhi(u32 u) { return __uint_as_float(u & 0xffff0000u); }

static __device__ __forceinline__ u32 pack2(float a, float b) {
  __hip_bfloat16 ha = __float2bfloat16(a);
  __hip_bfloat16 hb = __float2bfloat16(b);
  u16 ra, rb;
  __builtin_memcpy(&ra, &ha, 2);
  __builtin_memcpy(&rb, &hb, 2);
  return (u32)ra | ((u32)rb << 16);
}

static __device__ __forceinline__ u16 f2bf(float f) {
  u32 u = __float_as_uint(f);
  u32 r = (u + 0x7fffu + ((u >> 16) & 1u)) >> 16;
  return (u16)r;
}

static __device__ __forceinline__ bf16x8 as_bf(uint4 v) {
  bf16x8 r;
  __builtin_memcpy(&r, &v, 16);
  return r;
}

// truncating pack of two blended f32 -> bf16x2, single v_perm_b32
static __device__ __forceinline__ u32 packtrunc(float lo, float hi) {
  return __builtin_amdgcn_perm(__float_as_uint(hi), __float_as_uint(lo), 0x07060302u);
}

static __device__ __forceinline__ f32x2 unpk(u32 u) {
  f32x2 r;
  r.x = bflo(u);
  r.y = bfhi(u);
  return r;
}

// 4-corner bilinear blend of 8 bf16 channels -> bf16x8 fragment (as uint4)
static __device__ __forceinline__ uint4 blend4(uint4 a, uint4 b, uint4 c, uint4 d,
                                               float w00, float w01, float w10, float w11) {
  uint4 r;
#pragma unroll
  for (int j = 0; j < 4; j++) {
    f32x2 v = unpk((&a.x)[j]) * w00;
    v += unpk((&b.x)[j]) * w01;
    v += unpk((&c.x)[j]) * w10;
    v += unpk((&d.x)[j]) * w11;
    (&r.x)[j] = packtrunc(v.x, v.y);
  }
  return r;
}

// ---- kernel 1: x [B,C,H,W] f32 -> xT [B,H,W,C] bf16 (float4 loads) ----------
__global__ __launch_bounds__(256) void transpose_k(const float* __restrict__ x,
                                                   u16* __restrict__ xT) {
  const int bid = blockIdx.x;
  const int b = bid >> 6, y = bid & 63;
  const int t = threadIdx.x;
  const int cg = t >> 4;            // channel-group: channels cg*8..cg*8+7
  const int w4 = (t & 15) * 4;      // 4 consecutive w per thread
  const float* xp = x + ((size_t)(b * 128) * 64 + y) * 64;
  u16* op = xT + ((size_t)(b * 64 + y) * 64) * 128;
  float4 v[8];
#pragma unroll
  for (int k = 0; k < 8; k++)
    v[k] = *(const float4*)(xp + (cg * 8 + k) * 4096 + w4);
#pragma unroll
  for (int ww = 0; ww < 4; ww++) {
    u32 rr[4];
#pragma unroll
    for (int p = 0; p < 4; p++)
      rr[p] = pack2(((const float*)&v[2 * p])[ww], ((const float*)&v[2 * p + 1])[ww]);
    uint4 r;
    r.x = rr[0]; r.y = rr[1]; r.z = rr[2]; r.w = rr[3];
    *(uint4*)(op + (w4 + ww) * 128 + cg * 8) = r;
  }
}

// ---- kernel 2: weff via LDS-staged w-slice ----------------------------------
// grid 144 = ks(72) x nh(2). Output element idx = ((ks*6+nt)*64+lg*16+lrow)*8+j,
// n = nt*16+lrow, kc = lg*8+j.
__global__ __launch_bounds__(256) void weff_k(const float* __restrict__ w0,
                                              const float* __restrict__ w1,
                                              const float* __restrict__ wf,
                                              u16* __restrict__ weffg) {
  __shared__ float ws[84][32];
  const int blk = blockIdx.x;
  const int ks = blk >> 1, nh = blk & 1;
  const int br = ks >= 36 ? 1 : 0;
  const int ksb = ks - br * 36;
  const int tap = ksb >> 2, chunk = ksb & 3;
  const float* w = br ? w1 : w0;
  const int t = threadIdx.x;
  for (int i = t; i < 2688; i += 256) {
    int oc = i >> 5, kc = i & 31;
    ws[oc][kc] = w[oc * 1152 + (chunk * 32 + kc) * 9 + tap];
  }
  __syncthreads();
  const int kc = t & 31, ng = t >> 5;   // ng 0..7
  const int n0 = nh * 48 + ng * 6;
  float accv[6] = {0.f, 0.f, 0.f, 0.f, 0.f, 0.f};
#pragma unroll 4
  for (int oc = 0; oc < 84; oc++) {
    float wv_ = ws[oc][kc];
#pragma unroll
    for (int i = 0; i < 6; i++) {
      int n = n0 + i;
      float f = (n < 84) ? wf[n * 168 + br * 84 + oc] : 0.f;
      accv[i] += f * wv_;
    }
  }
#pragma unroll
  for (int i = 0; i < 6; i++) {
    int n = n0 + i;
    int nt = n >> 4, lrow = n & 15, lg = kc >> 3, j = kc & 7;
    int idx = ((ks * 6 + nt) * 64 + lg * 16 + lrow) * 8 + j;
    weffg[idx] = f2bf(n < 84 ? accv[i] : 0.f);
  }
}

// ---- kernel 3: small-window LDS deform-sample + GEMM, 2 blocks/CU -----------
// 2048 blocks = (b:8 -> XCD) x (h:64) x (quarter:4), 512 threads (8 waves).
// Block covers 16 px; window = 9 rows x 24 x-cols x 128 ch bf16 = 56.25 KB LDS
// -> 2 blocks/CU (vs r10's 146KB -> 1). 8 waves = 8-way K-split:
// wv = th*4 + br*2 + cp (th = tap-half {0..4 | 5..8}).
// __launch_bounds__(512,1) -> 128-VGPR cap (proven no-spill shape, r10).
// Toolchain law (r4/r6/r11/r12): cap = 512/(2 x block-waves-per-SIMD); no
// attribute overrides it, so 2x512-thr blocks is the only route to 16 waves/CU.
__global__ __launch_bounds__(512, 1) void deform_main(
    const u16* __restrict__ xT, const u16* __restrict__ weffg,
    const float* __restrict__ dm0, const float* __restrict__ dm1,
    const float* __restrict__ bias, float* __restrict__ out) {
  __shared__ uint4 window[3600];   // [(row*16 + slot)*25 + x], 57.6 KB

  const int t = threadIdx.x;
  const int wv = t >> 6, lane = t & 63;
  const int th = wv >> 2;              // tap-half: 0 -> taps 0..4, 1 -> 5..8
  const int sub = wv & 3;              // br*2 + cp
  const int br = sub >> 1, cp = sub & 1;
  const int lrow = lane & 15, lg = lane >> 4;
  const int blk = blockIdx.x;
  const int b = blk & 7;
  const int h = (blk >> 3) & 63;
  const int px0 = (blk >> 9) * 16;
  const int wx0 = min(40, max(0, px0 - 4));   // window x-origin (24 cols)

  const u16* xb = xT + (size_t)b * 524288;

  // ---- stage rows [h-4,h+4] x [wx0, wx0+23] into LDS (coalesced) ----
#pragma unroll
  for (int k = 0; k < 7; k++) {
    int u = t + (k << 9);          // < 3456 = 9*24*16
    if (u < 3456) {
      int row = u / 384;           // 384 = 24*16
      int rem = u - row * 384;
      int xx = rem >> 4, s = rem & 15;
      int ysr = min(63, max(0, h - 4 + row));
      uint4 v = *(const uint4*)(xb + ysr * 8192 + (wx0 + xx) * 128 + s * 8);
      window[(row * 16 + s) * 25 + xx] = v;
    }
  }
  __syncthreads();

  const float* dmb = (br ? dm1 : dm0) + (size_t)b * 73728 + h * 64 + px0 + lrow;
  const u16* wbase = weffg + (size_t)(br * 36 + cp * 2) * 3072 + lane * 8;
  const int t0 = th ? 5 : 0, t1 = th ? 9 : 5;

  f32x4 acc[6];
#pragma unroll
  for (int i = 0; i < 6; i++) acc[i] = f32x4{0.f, 0.f, 0.f, 0.f};

  float w00, w01, w10, w11;
  int x0A, x1A, yw0A, yw1A;            // clamped global x; window-rel rows
  float dyN, dxN;
  uint4 q[8];                          // 2 chunks x 4 corners in flight

  auto tapstate = [&](int ty, int tx, float dy, float dx) {
    float pyf = (float)(h + ty - 1) + dy;
    float pxf = (float)(px0 + lrow + tx - 1) + dx;
    float y0f = floorf(pyf), x0f = floorf(pxf);
    int y0 = (int)y0f, x0 = (int)x0f;
    float wy1 = pyf - y0f, wx1 = pxf - x0f;
    float wy0 = 1.f - wy1, wx0f = 1.f - wx1;
    int y1 = y0 + 1, x1 = x0 + 1;
    wy0 *= ((u32)y0 < 64u) ? 1.f : 0.f;
    wy1 *= ((u32)y1 < 64u) ? 1.f : 0.f;
    wx0f *= ((u32)x0 < 64u) ? 1.f : 0.f;
    wx1 *= ((u32)x1 < 64u) ? 1.f : 0.f;
    w00 = wy0 * wx0f; w01 = wy0 * wx1;
    w10 = wy1 * wx0f; w11 = wy1 * wx1;
    int y0c = min(63, max(0, y0)), y1c = min(63, max(0, y1));
    x0A = min(63, max(0, x0));
    x1A = min(63, max(0, x1));
    yw0A = y0c - h + 4;                // in-window iff 0..8
    yw1A = y1c - h + 4;
  };

  auto issue_lds = [&]() {
    int y0w = min(8, max(0, yw0A));
    int y1w = min(8, max(0, yw1A));
    int xw0 = min(23, max(0, x0A - wx0));
    int xw1 = min(23, max(0, x1A - wx0));
#pragma unroll
    for (int c = 0; c < 2; c++) {
      int slot = cp * 8 + c * 4 + lg;
      int b0 = (y0w * 16 + slot) * 25;
      int b1 = (y1w * 16 + slot) * 25;
      q[c * 4 + 0] = window[b0 + xw0];
      q[c * 4 + 1] = window[b0 + xw1];
      q[c * 4 + 2] = window[b1 + xw0];
      q[c * 4 + 3] = window[b1 + xw1];
    }
  };

  // rare out-of-window fallback: per-corner predicated global loads
  auto oow_fix = [&]() {
    bool by0 = (u32)yw0A > 8u, by1 = (u32)yw1A > 8u;
    bool bx0 = (u32)(x0A - wx0) > 23u, bx1 = (u32)(x1A - wx0) > 23u;
    if (__any(by0 | by1 | bx0 | bx1)) {
      const u16* base = xb + cp * 64 + lg * 8;
      int gy0 = (yw0A + h - 4) * 8192, gy1 = (yw1A + h - 4) * 8192;
      if (by0 | bx0) {
        q[0] = *(const uint4*)(base + gy0 + x0A * 128);
        q[4] = *(const uint4*)(base + gy0 + x0A * 128 + 32);
      }
      if (by0 | bx1) {
        q[1] = *(const uint4*)(base + gy0 + x1A * 128);
        q[5] = *(const uint4*)(base + gy0 + x1A * 128 + 32);
      }
      if (by1 | bx0) {
        q[2] = *(const uint4*)(base + gy1 + x0A * 128);
        q[6] = *(const uint4*)(base + gy1 + x0A * 128 + 32);
      }
      if (by1 | bx1) {
        q[3] = *(const uint4*)(base + gy1 + x1A * 128);
        q[7] = *(const uint4*)(base + gy1 + x1A * 128 + 32);
      }
    }
  };

  // ---- prologue: tap t0 state + reads, dm(t0+1) ----
  {
    float dy0 = dmb[(2 * t0) * 4096], dx0 = dmb[(2 * t0 + 1) * 4096];
    int ty = (t0 * 11) >> 5;
    tapstate(ty, t0 - ty * 3, dy0, dx0);
  }
  issue_lds();
  oow_fix();
  if (t0 + 1 < t1) {
    dyN = dmb[(2 * t0 + 2) * 4096];
    dxN = dmb[(2 * t0 + 3) * 4096];
  }

#pragma unroll 1
  for (int tap = t0; tap < t1; tap++) {
    const u16* wp = wbase + (size_t)(tap * 4) * 3072;

    // ---- chunk c=0 ----
    {
      uint4 wq0 = *(const uint4*)(wp);
      uint4 wq1 = *(const uint4*)(wp + 512);
      uint4 wq2 = *(const uint4*)(wp + 1024);
      uint4 wq3 = *(const uint4*)(wp + 1536);
      uint4 wq4 = *(const uint4*)(wp + 2048);
      uint4 wq5 = *(const uint4*)(wp + 2560);
      uint4 a0 = blend4(q[0], q[1], q[2], q[3], w00, w01, w10, w11);
      bf16x8 af0 = as_bf(a0);
      __builtin_amdgcn_s_setprio(1);
      acc[0] = __builtin_amdgcn_mfma_f32_16x16x32_bf16(as_bf(wq0), af0, acc[0], 0, 0, 0);
      acc[1] = __builtin_amdgcn_mfma_f32_16x16x32_bf16(as_bf(wq1), af0, acc[1], 0, 0, 0);
      acc[2] = __builtin_amdgcn_mfma_f32_16x16x32_bf16(as_bf(wq2), af0, acc[2], 0, 0, 0);
      acc[3] = __builtin_amdgcn_mfma_f32_16x16x32_bf16(as_bf(wq3), af0, acc[3], 0, 0, 0);
      acc[4] = __builtin_amdgcn_mfma_f32_16x16x32_bf16(as_bf(wq4), af0, acc[4], 0, 0, 0);
      acc[5] = __builtin_amdgcn_mfma_f32_16x16x32_bf16(as_bf(wq5), af0, acc[5], 0, 0, 0);
      __builtin_amdgcn_s_setprio(0);
    }

    // ---- chunk c=1 ----
    {
      uint4 wq0 = *(const uint4*)(wp + 3072);
      uint4 wq1 = *(const uint4*)(wp + 3584);
      uint4 wq2 = *(const uint4*)(wp + 4096);
      uint4 wq3 = *(const uint4*)(wp + 4608);
      uint4 wq4 = *(const uint4*)(wp + 5120);
      uint4 wq5 = *(const uint4*)(wp + 5632);
      uint4 a1 = blend4(q[4], q[5], q[6], q[7], w00, w01, w10, w11);

      // next tap: state + ds-issue (q now dead), dm prefetch a tap ahead
      if (tap + 1 < t1) {
        int tn = tap + 1;
        int ty = (tn * 11) >> 5;
        tapstate(ty, tn - ty * 3, dyN, dxN);
        issue_lds();
        oow_fix();
        if (tn + 1 < t1) {
          dyN = dmb[(2 * tn + 2) * 4096];
          dxN = dmb[(2 * tn + 3) * 4096];
        }
      }

      bf16x8 af1 = as_bf(a1);
      __builtin_amdgcn_s_setprio(1);
      acc[0] = __builtin_amdgcn_mfma_f32_16x16x32_bf16(as_bf(wq0), af1, acc[0], 0, 0, 0);
      acc[1] = __builtin_amdgcn_mfma_f32_16x16x32_bf16(as_bf(wq1), af1, acc[1], 0, 0, 0);
      acc[2] = __builtin_amdgcn_mfma_f32_16x16x32_bf16(as_bf(wq2), af1, acc[2], 0, 0, 0);
      acc[3] = __builtin_amdgcn_mfma_f32_16x16x32_bf16(as_bf(wq3), af1, acc[3], 0, 0, 0);
      acc[4] = __builtin_amdgcn_mfma_f32_16x16x32_bf16(as_bf(wq4), af1, acc[4], 0, 0, 0);
      acc[5] = __builtin_amdgcn_mfma_f32_16x16x32_bf16(as_bf(wq5), af1, acc[5], 0, 0, 0);
      __builtin_amdgcn_s_setprio(0);
    }
  }

  // ---- reduce the 8 K-partials (reuse window LDS), store ----
  __syncthreads();                       // all window reads done
  if (wv > 0) {
#pragma unroll
    for (int nt = 0; nt < 6; nt++) {
      uint4 v;
      __builtin_memcpy(&v, &acc[nt], 16);
      window[(wv - 1) * 384 + nt * 64 + lane] = v;
    }
  }
  __syncthreads();
  if (wv == 0) {
#pragma unroll
    for (int nt = 0; nt < 6; nt++) {
      for (int r = 0; r < 7; r++) {
        uint4 v = window[r * 384 + nt * 64 + lane];
        f32x4 fv;
        __builtin_memcpy(&fv, &v, 16);
#pragma unroll
        for (int j = 0; j < 4; j++) acc[nt][j] += fv[j];
      }
    }
    float* op = out + ((size_t)b * 84 * 64 + h) * 64 + px0;
#pragma unroll
    for (int nt = 0; nt < 6; nt++) {
#pragma unroll
      for (int j = 0; j < 4; j++) {
        int o = nt * 16 + lg * 4 + j;
        if (o < 84) op[(size_t)o * 4096 + lrow] = acc[nt][j] + bias[o];
      }
    }
  }
}

// ---- launch -----------------------------------------------------------------
extern "C" void kernel_launch(void* const* d_in, const int* in_sizes, int n_in,
                              void* d_out, int out_size, void* d_ws, size_t ws_size,
                              hipStream_t stream) {
  const float* x   = (const float*)d_in[0];
  const float* dm0 = (const float*)d_in[1];
  const float* dm1 = (const float*)d_in[2];
  const float* w0  = (const float*)d_in[3];
  const float* w1  = (const float*)d_in[4];
  const float* wf  = (const float*)d_in[5];
  const float* bf  = (const float*)d_in[6];
  float* out = (float*)d_out;

  u16* xT = (u16*)d_ws;                                               // 8 MiB
  u16* weffg = (u16*)((char*)d_ws + (size_t)8 * 64 * 64 * 128 * 2);   // 432 KiB

  transpose_k<<<512, 256, 0, stream>>>(x, xT);
  weff_k<<<144, 256, 0, stream>>>(w0, w1, wf, weffg);
  deform_main<<<2048, 512, 0, stream>>>(xT, weffg, dm0, dm1, bf, out);
}

// Round 15
// 70.821 us; speedup vs baseline: 1.2008x; 1.2008x over previous
//
#include <hip/hip_runtime.h>
#include <hip/hip_bf16.h>

using u16 = unsigned short;
using u32 = unsigned int;
typedef float f32x4 __attribute__((ext_vector_type(4)));
typedef float f32x2 __attribute__((ext_vector_type(2)));
typedef __bf16 bf16x8 __attribute__((ext_vector_type(8)));

// ---- helpers ----------------------------------------------------------------
static __device__ __forceinline__ float bflo(u32 u) { return __uint_as_float(u << 16); }
static __device__ __forceinline__ float bfhi(u32 u) { return __uint_as_float(u & 0xffff0000u); }

// RNE pack of two f32 -> bf16x2 (a in low half) — numerics identical to the
// old transpose_k path.
static __device__ __forceinline__ u32 pack2(float a, float b) {
  __hip_bfloat16 ha = __float2bfloat16(a);
  __hip_bfloat16 hb = __float2bfloat16(b);
  u16 ra, rb;
  __builtin_memcpy(&ra, &ha, 2);
  __builtin_memcpy(&rb, &hb, 2);
  return (u32)ra | ((u32)rb << 16);
}

static __device__ __forceinline__ u16 f2bf(float f) {
  u32 u = __float_as_uint(f);
  u32 r = (u + 0x7fffu + ((u >> 16) & 1u)) >> 16;
  return (u16)r;
}

static __device__ __forceinline__ bf16x8 as_bf(uint4 v) {
  bf16x8 r;
  __builtin_memcpy(&r, &v, 16);
  return r;
}

// truncating pack of two blended f32 -> bf16x2, single v_perm_b32
static __device__ __forceinline__ u32 packtrunc(float lo, float hi) {
  return __builtin_amdgcn_perm(__float_as_uint(hi), __float_as_uint(lo), 0x07060302u);
}

static __device__ __forceinline__ f32x2 unpk(u32 u) {
  f32x2 r;
  r.x = bflo(u);
  r.y = bfhi(u);
  return r;
}

// 4-corner bilinear blend of 8 bf16 channels -> bf16x8 fragment (as uint4)
static __device__ __forceinline__ uint4 blend4(uint4 a, uint4 b, uint4 c, uint4 d,
                                               float w00, float w01, float w10, float w11) {
  uint4 r;
#pragma unroll
  for (int j = 0; j < 4; j++) {
    f32x2 v = unpk((&a.x)[j]) * w00;
    v += unpk((&b.x)[j]) * w01;
    v += unpk((&c.x)[j]) * w10;
    v += unpk((&d.x)[j]) * w11;
    (&r.x)[j] = packtrunc(v.x, v.y);
  }
  return r;
}

// ---- kernel 1: weff via LDS-staged w-slice ----------------------------------
// grid 144 = ks(72) x nh(2). Output element idx = ((ks*6+nt)*64+lg*16+lrow)*8+j,
// n = nt*16+lrow, kc = lg*8+j.
__global__ __launch_bounds__(256) void weff_k(const float* __restrict__ w0,
                                              const float* __restrict__ w1,
                                              const float* __restrict__ wf,
                                              u16* __restrict__ weffg) {
  __shared__ float ws[84][32];
  const int blk = blockIdx.x;
  const int ks = blk >> 1, nh = blk & 1;
  const int br = ks >= 36 ? 1 : 0;
  const int ksb = ks - br * 36;
  const int tap = ksb >> 2, chunk = ksb & 3;
  const float* w = br ? w1 : w0;
  const int t = threadIdx.x;
  for (int i = t; i < 2688; i += 256) {
    int oc = i >> 5, kc = i & 31;
    ws[oc][kc] = w[oc * 1152 + (chunk * 32 + kc) * 9 + tap];
  }
  __syncthreads();
  const int kc = t & 31, ng = t >> 5;   // ng 0..7
  const int n0 = nh * 48 + ng * 6;
  float accv[6] = {0.f, 0.f, 0.f, 0.f, 0.f, 0.f};
#pragma unroll 4
  for (int oc = 0; oc < 84; oc++) {
    float wv_ = ws[oc][kc];
#pragma unroll
    for (int i = 0; i < 6; i++) {
      int n = n0 + i;
      float f = (n < 84) ? wf[n * 168 + br * 84 + oc] : 0.f;
      accv[i] += f * wv_;
    }
  }
#pragma unroll
  for (int i = 0; i < 6; i++) {
    int n = n0 + i;
    int nt = n >> 4, lrow = n & 15, lg = kc >> 3, j = kc & 7;
    int idx = ((ks * 6 + nt) * 64 + lg * 16 + lrow) * 8 + j;
    weffg[idx] = f2bf(n < 84 ? accv[i] : 0.f);
  }
}

// ---- kernel 2: fused transpose + LDS-window deform-sample + GEMM ------------
// r15 = r10's proven core EXACTLY (acc[6][2], q[16], two 16-px fragments per
// wave — r14's bug was dropping the f dimension: pixels 16-31/48-63 were never
// computed, absmax 3.92 = stub signature), with only two patches:
//  (1) staging builds the window from x (f32 NCHW) with in-register RNE pack;
//  (2) OOW fallback reads x directly. transpose_k deleted.
// 512 blocks = (b:8 -> XCD) x (h:64), 512 threads (8 waves).
// Wave wv: pxh = wv>>2 (32-px half), sub = wv&3 -> br = sub>>1, cp = sub&1.
__global__ __launch_bounds__(512, 1) void deform_main(
    const float* __restrict__ x, const u16* __restrict__ weffg,
    const float* __restrict__ dm0, const float* __restrict__ dm1,
    const float* __restrict__ bias, float* __restrict__ out) {
  __shared__ uint4 ldsbuf[9360];   // 9 rows * 16 slots * 65 * 16B = 146.25 KiB

  const int t = threadIdx.x;
  const int wv = t >> 6, lane = t & 63;
  const int pxh = wv >> 2, sub = wv & 3;
  const int br = sub >> 1, cp = sub & 1;
  const int lrow = lane & 15, lg = lane >> 4;
  const int blk = blockIdx.x;
  const int b = blk & 7, h = blk >> 3;
  const int px0 = pxh * 32;

  const float* xsrc = x + (size_t)b * 524288;   // b*128*64*64

  // ---- stage rows [h-4, h+4] from x, converting f32->bf16 in-register ----
  // u = i*1024 + s*64 + xx : row i, slot s (8 channels), x-pos xx.
  // Per scalar load: 64 lanes = consecutive xx = 256B coalesced.
#pragma unroll
  for (int k = 0; k < 18; k++) {
    int u = t + (k << 9);          // < 9216
    int i = u >> 10;               // window row 0..8
    int ul = u & 1023;
    int s = ul >> 6, xx = ul & 63;
    int ysr = min(63, max(0, h - 4 + i));
    const float* p = xsrc + (s * 8) * 4096 + ysr * 64 + xx;
    u32 rr[4];
#pragma unroll
    for (int e = 0; e < 4; e++)
      rr[e] = pack2(p[(2 * e) * 4096], p[(2 * e + 1) * 4096]);
    uint4 v;
    v.x = rr[0]; v.y = rr[1]; v.z = rr[2]; v.w = rr[3];
    ldsbuf[(i * 16 + s) * 65 + xx] = v;
  }
  __syncthreads();

  const float* dmb = (br ? dm1 : dm0) + (size_t)b * 73728 + h * 64 + px0 + lrow;
  const u16* wbase = weffg + (size_t)(br * 36 + cp * 2) * 3072 + lane * 8;

  f32x4 acc[6][2];
#pragma unroll
  for (int i = 0; i < 6; i++)
#pragma unroll
    for (int f = 0; f < 2; f++) acc[i][f] = f32x4{0.f, 0.f, 0.f, 0.f};

  float w00a[2], w01a[2], w10a[2], w11a[2];
  int x0a[2], x1a[2], yw0a[2], yw1a[2];   // yw*: window-relative rows (may be OOW)
  float dyN[2], dxN[2];
  uint4 q[16];                            // [c][f][corner] in flight (1 tap ahead)
  uint4 wA0, wA1, wA2, wA3, wA4, wA5;     // weff ping
  uint4 wB0, wB1, wB2, wB3, wB4, wB5;     // weff pong

  auto tapstate = [&](int f, int ty, int tx, float dy, float dx) {
    float pyf = (float)(h + ty - 1) + dy;
    float pxf = (float)(px0 + f * 16 + lrow + tx - 1) + dx;
    float y0f = floorf(pyf), x0f = floorf(pxf);
    int y0 = (int)y0f, x0 = (int)x0f;
    float wy1 = pyf - y0f, wx1 = pxf - x0f;
    float wy0 = 1.f - wy1, wx0 = 1.f - wx1;
    int y1 = y0 + 1, x1 = x0 + 1;
    wy0 *= ((u32)y0 < 64u) ? 1.f : 0.f;
    wy1 *= ((u32)y1 < 64u) ? 1.f : 0.f;
    wx0 *= ((u32)x0 < 64u) ? 1.f : 0.f;
    wx1 *= ((u32)x1 < 64u) ? 1.f : 0.f;
    w00a[f] = wy0 * wx0; w01a[f] = wy0 * wx1;
    w10a[f] = wy1 * wx0; w11a[f] = wy1 * wx1;
    int y0c = min(63, max(0, y0)), y1c = min(63, max(0, y1));
    x0a[f] = min(63, max(0, x0));
    x1a[f] = min(63, max(0, x1));
    yw0a[f] = y0c - h + 4;                // in-window iff 0..8
    yw1a[f] = y1c - h + 4;
  };

  // issue all 16 ds_read corners for the current tap
  auto issue_lds = [&]() {
#pragma unroll
    for (int c = 0; c < 2; c++) {
      int slot = cp * 8 + c * 4 + lg;
#pragma unroll
      for (int f = 0; f < 2; f++) {
        int y0w = min(8, max(0, yw0a[f]));
        int y1w = min(8, max(0, yw1a[f]));
        int b0 = (y0w * 16 + slot) * 65;
        int b1 = (y1w * 16 + slot) * 65;
        q[c * 8 + f * 4 + 0] = ldsbuf[b0 + x0a[f]];
        q[c * 8 + f * 4 + 1] = ldsbuf[b0 + x1a[f]];
        q[c * 8 + f * 4 + 2] = ldsbuf[b1 + x0a[f]];
        q[c * 8 + f * 4 + 3] = ldsbuf[b1 + x1a[f]];
      }
    }
  };

  // rare out-of-window fallback: predicated loads straight from x (f32+pack)
  auto oow_fix = [&]() {
    bool bad = ((u32)yw0a[0] > 8u) | ((u32)yw1a[0] > 8u) |
               ((u32)yw0a[1] > 8u) | ((u32)yw1a[1] > 8u);
    if (__any(bad)) {
#pragma unroll
      for (int f = 0; f < 2; f++) {
        if ((u32)yw0a[f] > 8u) {
          int gy = (yw0a[f] + h - 4) * 64;
#pragma unroll
          for (int c = 0; c < 2; c++) {
            u32 r0[4], r1[4];
#pragma unroll
            for (int e = 0; e < 4; e++) {
              const float* pc = xsrc + (size_t)(cp * 64 + c * 32 + lg * 8 + 2 * e) * 4096 + gy;
              r0[e] = pack2(pc[x0a[f]], pc[4096 + x0a[f]]);
              r1[e] = pack2(pc[x1a[f]], pc[4096 + x1a[f]]);
            }
            uint4 v0, v1;
            v0.x = r0[0]; v0.y = r0[1]; v0.z = r0[2]; v0.w = r0[3];
            v1.x = r1[0]; v1.y = r1[1]; v1.z = r1[2]; v1.w = r1[3];
            q[c * 8 + f * 4 + 0] = v0;
            q[c * 8 + f * 4 + 1] = v1;
          }
        }
        if ((u32)yw1a[f] > 8u) {
          int gy = (yw1a[f] + h - 4) * 64;
#pragma unroll
          for (int c = 0; c < 2; c++) {
            u32 r0[4], r1[4];
#pragma unroll
            for (int e = 0; e < 4; e++) {
              const float* pc = xsrc + (size_t)(cp * 64 + c * 32 + lg * 8 + 2 * e) * 4096 + gy;
              r0[e] = pack2(pc[x0a[f]], pc[4096 + x0a[f]]);
              r1[e] = pack2(pc[x1a[f]], pc[4096 + x1a[f]]);
            }
            uint4 v0, v1;
            v0.x = r0[0]; v0.y = r0[1]; v0.z = r0[2]; v0.w = r0[3];
            v1.x = r1[0]; v1.y = r1[1]; v1.z = r1[2]; v1.w = r1[3];
            q[c * 8 + f * 4 + 2] = v0;
            q[c * 8 + f * 4 + 3] = v1;
          }
        }
      }
    }
  };

  // ---- prologue: tap 0 state + reads, dm(tap1), weff step0 ----
  {
    float dy0 = dmb[0], dx0 = dmb[4096];
    float dy1 = dmb[16], dx1 = dmb[4096 + 16];
    tapstate(0, 0, 0, dy0, dx0);
    tapstate(1, 0, 0, dy1, dx1);
  }
  issue_lds();
  oow_fix();
  dyN[0] = dmb[2 * 4096];      dxN[0] = dmb[3 * 4096];
  dyN[1] = dmb[2 * 4096 + 16]; dxN[1] = dmb[3 * 4096 + 16];
  {
    const u16* wp = wbase;   // (tap0, c0)
    wA0 = *(const uint4*)(wp);        wA1 = *(const uint4*)(wp + 512);
    wA2 = *(const uint4*)(wp + 1024); wA3 = *(const uint4*)(wp + 1536);
    wA4 = *(const uint4*)(wp + 2048); wA5 = *(const uint4*)(wp + 2560);
  }

#pragma unroll 1
  for (int tap = 0; tap < 9; tap++) {
    // ---- chunk c=0: consume wA ----
    {
      const u16* wpB = wbase + (size_t)(tap * 4 + 1) * 3072;
      wB0 = *(const uint4*)(wpB);        wB1 = *(const uint4*)(wpB + 512);
      wB2 = *(const uint4*)(wpB + 1024); wB3 = *(const uint4*)(wpB + 1536);
      wB4 = *(const uint4*)(wpB + 2048); wB5 = *(const uint4*)(wpB + 2560);

      uint4 a0 = blend4(q[0], q[1], q[2], q[3], w00a[0], w01a[0], w10a[0], w11a[0]);
      uint4 a1 = blend4(q[4], q[5], q[6], q[7], w00a[1], w01a[1], w10a[1], w11a[1]);
      bf16x8 af0 = as_bf(a0), af1 = as_bf(a1);
      __builtin_amdgcn_s_setprio(1);
      acc[0][0] = __builtin_amdgcn_mfma_f32_16x16x32_bf16(as_bf(wA0), af0, acc[0][0], 0, 0, 0);
      acc[1][0] = __builtin_amdgcn_mfma_f32_16x16x32_bf16(as_bf(wA1), af0, acc[1][0], 0, 0, 0);
      acc[2][0] = __builtin_amdgcn_mfma_f32_16x16x32_bf16(as_bf(wA2), af0, acc[2][0], 0, 0, 0);
      acc[3][0] = __builtin_amdgcn_mfma_f32_16x16x32_bf16(as_bf(wA3), af0, acc[3][0], 0, 0, 0);
      acc[4][0] = __builtin_amdgcn_mfma_f32_16x16x32_bf16(as_bf(wA4), af0, acc[4][0], 0, 0, 0);
      acc[5][0] = __builtin_amdgcn_mfma_f32_16x16x32_bf16(as_bf(wA5), af0, acc[5][0], 0, 0, 0);
      acc[0][1] = __builtin_amdgcn_mfma_f32_16x16x32_bf16(as_bf(wA0), af1, acc[0][1], 0, 0, 0);
      acc[1][1] = __builtin_amdgcn_mfma_f32_16x16x32_bf16(as_bf(wA1), af1, acc[1][1], 0, 0, 0);
      acc[2][1] = __builtin_amdgcn_mfma_f32_16x16x32_bf16(as_bf(wA2), af1, acc[2][1], 0, 0, 0);
      acc[3][1] = __builtin_amdgcn_mfma_f32_16x16x32_bf16(as_bf(wA3), af1, acc[3][1], 0, 0, 0);
      acc[4][1] = __builtin_amdgcn_mfma_f32_16x16x32_bf16(as_bf(wA4), af1, acc[4][1], 0, 0, 0);
      acc[5][1] = __builtin_amdgcn_mfma_f32_16x16x32_bf16(as_bf(wA5), af1, acc[5][1], 0, 0, 0);
      __builtin_amdgcn_s_setprio(0);
    }

    // ---- chunk c=1: consume wB ----
    {
      if (tap < 8) {
        const u16* wpA = wbase + (size_t)((tap + 1) * 4) * 3072;
        wA0 = *(const uint4*)(wpA);        wA1 = *(const uint4*)(wpA + 512);
        wA2 = *(const uint4*)(wpA + 1024); wA3 = *(const uint4*)(wpA + 1536);
        wA4 = *(const uint4*)(wpA + 2048); wA5 = *(const uint4*)(wpA + 2560);
      }

      uint4 a2 = blend4(q[8], q[9], q[10], q[11], w00a[0], w01a[0], w10a[0], w11a[0]);
      uint4 a3 = blend4(q[12], q[13], q[14], q[15], w00a[1], w01a[1], w10a[1], w11a[1]);

      // next tap: state + ds-issue (q now dead), dm prefetch 2 taps ahead
      if (tap < 8) {
        int tn = tap + 1;
        int ty = (tn * 11) >> 5;     // tn/3
        int tx = tn - ty * 3;
        tapstate(0, ty, tx, dyN[0], dxN[0]);
        tapstate(1, ty, tx, dyN[1], dxN[1]);
        issue_lds();
        oow_fix();
        if (tap < 7) {
          dyN[0] = dmb[(2 * tn + 2) * 4096];      dxN[0] = dmb[(2 * tn + 3) * 4096];
          dyN[1] = dmb[(2 * tn + 2) * 4096 + 16]; dxN[1] = dmb[(2 * tn + 3) * 4096 + 16];
        }
      }

      bf16x8 af2 = as_bf(a2), af3 = as_bf(a3);
      __builtin_amdgcn_s_setprio(1);
      acc[0][0] = __builtin_amdgcn_mfma_f32_16x16x32_bf16(as_bf(wB0), af2, acc[0][0], 0, 0, 0);
      acc[1][0] = __builtin_amdgcn_mfma_f32_16x16x32_bf16(as_bf(wB1), af2, acc[1][0], 0, 0, 0);
      acc[2][0] = __builtin_amdgcn_mfma_f32_16x16x32_bf16(as_bf(wB2), af2, acc[2][0], 0, 0, 0);
      acc[3][0] = __builtin_amdgcn_mfma_f32_16x16x32_bf16(as_bf(wB3), af2, acc[3][0], 0, 0, 0);
      acc[4][0] = __builtin_amdgcn_mfma_f32_16x16x32_bf16(as_bf(wB4), af2, acc[4][0], 0, 0, 0);
      acc[5][0] = __builtin_amdgcn_mfma_f32_16x16x32_bf16(as_bf(wB5), af2, acc[5][0], 0, 0, 0);
      acc[0][1] = __builtin_amdgcn_mfma_f32_16x16x32_bf16(as_bf(wB0), af3, acc[0][1], 0, 0, 0);
      acc[1][1] = __builtin_amdgcn_mfma_f32_16x16x32_bf16(as_bf(wB1), af3, acc[1][1], 0, 0, 0);
      acc[2][1] = __builtin_amdgcn_mfma_f32_16x16x32_bf16(as_bf(wB2), af3, acc[2][1], 0, 0, 0);
      acc[3][1] = __builtin_amdgcn_mfma_f32_16x16x32_bf16(as_bf(wB3), af3, acc[3][1], 0, 0, 0);
      acc[4][1] = __builtin_amdgcn_mfma_f32_16x16x32_bf16(as_bf(wB4), af3, acc[4][1], 0, 0, 0);
      acc[5][1] = __builtin_amdgcn_mfma_f32_16x16x32_bf16(as_bf(wB5), af3, acc[5][1], 0, 0, 0);
      __builtin_amdgcn_s_setprio(0);
    }
  }

  // ---- reduce the 4 K-partials per px-half (reuse staging LDS), store ----
  __syncthreads();                       // all LDS gather reads done
  const int rbase = pxh * 2304;          // uint4 units; 2*2304 = 4608 <= 9360
  if (sub > 0) {
#pragma unroll
    for (int nt = 0; nt < 6; nt++)
#pragma unroll
      for (int f = 0; f < 2; f++) {
        uint4 v;
        __builtin_memcpy(&v, &acc[nt][f], 16);
        ldsbuf[rbase + ((sub - 1) * 12 + nt * 2 + f) * 64 + lane] = v;
      }
  }
  __syncthreads();
  if (sub == 0) {
#pragma unroll
    for (int nt = 0; nt < 6; nt++)
#pragma unroll
      for (int f = 0; f < 2; f++) {
#pragma unroll
        for (int r = 0; r < 3; r++) {
          uint4 v = ldsbuf[rbase + (r * 12 + nt * 2 + f) * 64 + lane];
          f32x4 fv;
          __builtin_memcpy(&fv, &v, 16);
#pragma unroll
          for (int j = 0; j < 4; j++) acc[nt][f][j] += fv[j];
        }
      }
    float* op = out + ((size_t)b * 84 * 64 + h) * 64 + px0;
#pragma unroll
    for (int nt = 0; nt < 6; nt++)
#pragma unroll
      for (int j = 0; j < 4; j++) {
        int o = nt * 16 + lg * 4 + j;
        if (o < 84) {
          float bv = bias[o];
#pragma unroll
          for (int f = 0; f < 2; f++)
            op[(size_t)o * 4096 + f * 16 + lrow] = acc[nt][f][j] + bv;
        }
      }
  }
}

// ---- launch -----------------------------------------------------------------
extern "C" void kernel_launch(void* const* d_in, const int* in_sizes, int n_in,
                              void* d_out, int out_size, void* d_ws, size_t ws_size,
                              hipStream_t stream) {
  const float* x   = (const float*)d_in[0];
  const float* dm0 = (const float*)d_in[1];
  const float* dm1 = (const float*)d_in[2];
  const float* w0  = (const float*)d_in[3];
  const float* w1  = (const float*)d_in[4];
  const float* wf  = (const float*)d_in[5];
  const float* bf  = (const float*)d_in[6];
  float* out = (float*)d_out;

  u16* weffg = (u16*)d_ws;   // 432 KiB

  weff_k<<<144, 256, 0, stream>>>(w0, w1, wf, weffg);
  deform_main<<<512, 512, 0, stream>>>(x, weffg, dm0, dm1, bf, out);
}

// Round 16
// 69.830 us; speedup vs baseline: 1.2178x; 1.0142x over previous
//
#include <hip/hip_runtime.h>
#include <hip/hip_bf16.h>

using u16 = unsigned short;
using u32 = unsigned int;
typedef float f32x4 __attribute__((ext_vector_type(4)));
typedef float f32x2 __attribute__((ext_vector_type(2)));
typedef __bf16 bf16x8 __attribute__((ext_vector_type(8)));

// ---- helpers ----------------------------------------------------------------
static __device__ __forceinline__ float bflo(u32 u) { return __uint_as_float(u << 16); }
static __device__ __forceinline__ float bfhi(u32 u) { return __uint_as_float(u & 0xffff0000u); }

// RNE pack of two f32 -> bf16x2 (a in low half)
static __device__ __forceinline__ u32 pack2(float a, float b) {
  __hip_bfloat16 ha = __float2bfloat16(a);
  __hip_bfloat16 hb = __float2bfloat16(b);
  u16 ra, rb;
  __builtin_memcpy(&ra, &ha, 2);
  __builtin_memcpy(&rb, &hb, 2);
  return (u32)ra | ((u32)rb << 16);
}

static __device__ __forceinline__ u16 f2bf(float f) {
  u32 u = __float_as_uint(f);
  u32 r = (u + 0x7fffu + ((u >> 16) & 1u)) >> 16;
  return (u16)r;
}

static __device__ __forceinline__ bf16x8 as_bf(uint4 v) {
  bf16x8 r;
  __builtin_memcpy(&r, &v, 16);
  return r;
}

// truncating pack of two f32 -> bf16x2 (lo in low half), single v_perm_b32
static __device__ __forceinline__ u32 packtrunc(float lo, float hi) {
  return __builtin_amdgcn_perm(__float_as_uint(hi), __float_as_uint(lo), 0x07060302u);
}

static __device__ __forceinline__ f32x2 unpk(u32 u) {
  f32x2 r;
  r.x = bflo(u);
  r.y = bfhi(u);
  return r;
}

// 4-corner bilinear blend of 8 bf16 channels -> bf16x8 fragment (as uint4)
static __device__ __forceinline__ uint4 blend4(uint4 a, uint4 b, uint4 c, uint4 d,
                                               float w00, float w01, float w10, float w11) {
  uint4 r;
#pragma unroll
  for (int j = 0; j < 4; j++) {
    f32x2 v = unpk((&a.x)[j]) * w00;
    v += unpk((&b.x)[j]) * w01;
    v += unpk((&c.x)[j]) * w10;
    v += unpk((&d.x)[j]) * w11;
    (&r.x)[j] = packtrunc(v.x, v.y);
  }
  return r;
}

// ---- kernel 1: weff via LDS-staged w-slice ----------------------------------
// grid 144 = ks(72) x nh(2). Output element idx = ((ks*6+nt)*64+lg*16+lrow)*8+j,
// n = nt*16+lrow, kc = lg*8+j.
__global__ __launch_bounds__(256) void weff_k(const float* __restrict__ w0,
                                              const float* __restrict__ w1,
                                              const float* __restrict__ wf,
                                              u16* __restrict__ weffg) {
  __shared__ float ws[84][32];
  const int blk = blockIdx.x;
  const int ks = blk >> 1, nh = blk & 1;
  const int br = ks >= 36 ? 1 : 0;
  const int ksb = ks - br * 36;
  const int tap = ksb >> 2, chunk = ksb & 3;
  const float* w = br ? w1 : w0;
  const int t = threadIdx.x;
  for (int i = t; i < 2688; i += 256) {
    int oc = i >> 5, kc = i & 31;
    ws[oc][kc] = w[oc * 1152 + (chunk * 32 + kc) * 9 + tap];
  }
  __syncthreads();
  const int kc = t & 31, ng = t >> 5;   // ng 0..7
  const int n0 = nh * 48 + ng * 6;
  float accv[6] = {0.f, 0.f, 0.f, 0.f, 0.f, 0.f};
#pragma unroll 4
  for (int oc = 0; oc < 84; oc++) {
    float wv_ = ws[oc][kc];
#pragma unroll
    for (int i = 0; i < 6; i++) {
      int n = n0 + i;
      float f = (n < 84) ? wf[n * 168 + br * 84 + oc] : 0.f;
      accv[i] += f * wv_;
    }
  }
#pragma unroll
  for (int i = 0; i < 6; i++) {
    int n = n0 + i;
    int nt = n >> 4, lrow = n & 15, lg = kc >> 3, j = kc & 7;
    int idx = ((ks * 6 + nt) * 64 + lg * 16 + lrow) * 8 + j;
    weffg[idx] = f2bf(n < 84 ? accv[i] : 0.f);
  }
}

// ---- kernel 2: fused transpose + LDS-window deform-sample + GEMM ------------
// r16 = r15 (r10's proven 2-fragment core + fused staging) with the staging
// arithmetic fixed (r15 lesson: 144 scalar loads + RNE packs cost +8us):
//  (1) float4 loads: 8 vec-loads + 4 uint4 LDS writes per work item
//      (loads/thread 144 -> ~40, same bytes, L2-resident);
//  (2) truncating v_perm pack (1 instr) instead of RNE (~5);
//  (3) dm + first-weff global loads hoisted above __syncthreads (latency
//      hidden under the staging barrier).
// 512 blocks = (b:8 -> XCD) x (h:64), 512 threads (8 waves).
// Wave wv: pxh = wv>>2 (32-px half), sub = wv&3 -> br = sub>>1, cp = sub&1.
__global__ __launch_bounds__(512, 1) void deform_main(
    const float* __restrict__ x, const u16* __restrict__ weffg,
    const float* __restrict__ dm0, const float* __restrict__ dm1,
    const float* __restrict__ bias, float* __restrict__ out) {
  __shared__ uint4 ldsbuf[9360];   // 9 rows * 16 slots * 65 * 16B = 146.25 KiB

  const int t = threadIdx.x;
  const int wv = t >> 6, lane = t & 63;
  const int pxh = wv >> 2, sub = wv & 3;
  const int br = sub >> 1, cp = sub & 1;
  const int lrow = lane & 15, lg = lane >> 4;
  const int blk = blockIdx.x;
  const int b = blk & 7, h = blk >> 3;
  const int px0 = pxh * 32;

  const float* xsrc = x + (size_t)b * 524288;   // b*128*64*64

  // ---- stage rows [h-4, h+4] from x with float4 loads ----
  // work item u = i*256 + s*16 + xg : row i, slot s (8 ch), x-group xg (4 px)
#pragma unroll
  for (int k = 0; k < 5; k++) {
    int u = t + (k << 9);          // < 2304 = 9*16*16
    if (u < 2304) {
      int xg = u & 15, s = (u >> 4) & 15, i = u >> 8;
      int ysr = min(63, max(0, h - 4 + i));
      const float* p = xsrc + (size_t)(s * 8) * 4096 + ysr * 64 + xg * 4;
      float4 f[8];
#pragma unroll
      for (int e = 0; e < 8; e++) f[e] = *(const float4*)(p + (size_t)e * 4096);
      int base = (i * 16 + s) * 65 + xg * 4;
#pragma unroll
      for (int ww = 0; ww < 4; ww++) {
        uint4 v;
        v.x = packtrunc(((const float*)&f[0])[ww], ((const float*)&f[1])[ww]);
        v.y = packtrunc(((const float*)&f[2])[ww], ((const float*)&f[3])[ww]);
        v.z = packtrunc(((const float*)&f[4])[ww], ((const float*)&f[5])[ww]);
        v.w = packtrunc(((const float*)&f[6])[ww], ((const float*)&f[7])[ww]);
        ldsbuf[base + ww] = v;
      }
    }
  }

  const float* dmb = (br ? dm1 : dm0) + (size_t)b * 73728 + h * 64 + px0 + lrow;
  const u16* wbase = weffg + (size_t)(br * 36 + cp * 2) * 3072 + lane * 8;

  // hoisted global loads: latency hides under the staging barrier
  float dy0 = dmb[0], dx0 = dmb[4096];
  float dy1 = dmb[16], dx1 = dmb[4096 + 16];
  float dyN[2], dxN[2];
  dyN[0] = dmb[2 * 4096];      dxN[0] = dmb[3 * 4096];
  dyN[1] = dmb[2 * 4096 + 16]; dxN[1] = dmb[3 * 4096 + 16];
  uint4 wA0, wA1, wA2, wA3, wA4, wA5;     // weff ping
  uint4 wB0, wB1, wB2, wB3, wB4, wB5;     // weff pong
  {
    const u16* wp = wbase;   // (tap0, c0)
    wA0 = *(const uint4*)(wp);        wA1 = *(const uint4*)(wp + 512);
    wA2 = *(const uint4*)(wp + 1024); wA3 = *(const uint4*)(wp + 1536);
    wA4 = *(const uint4*)(wp + 2048); wA5 = *(const uint4*)(wp + 2560);
  }

  __syncthreads();

  f32x4 acc[6][2];
#pragma unroll
  for (int i = 0; i < 6; i++)
#pragma unroll
    for (int f = 0; f < 2; f++) acc[i][f] = f32x4{0.f, 0.f, 0.f, 0.f};

  float w00a[2], w01a[2], w10a[2], w11a[2];
  int x0a[2], x1a[2], yw0a[2], yw1a[2];   // yw*: window-relative rows (may be OOW)
  uint4 q[16];                            // [c][f][corner] in flight (1 tap ahead)

  auto tapstate = [&](int f, int ty, int tx, float dy, float dx) {
    float pyf = (float)(h + ty - 1) + dy;
    float pxf = (float)(px0 + f * 16 + lrow + tx - 1) + dx;
    float y0f = floorf(pyf), x0f = floorf(pxf);
    int y0 = (int)y0f, x0 = (int)x0f;
    float wy1 = pyf - y0f, wx1 = pxf - x0f;
    float wy0 = 1.f - wy1, wx0 = 1.f - wx1;
    int y1 = y0 + 1, x1 = x0 + 1;
    wy0 *= ((u32)y0 < 64u) ? 1.f : 0.f;
    wy1 *= ((u32)y1 < 64u) ? 1.f : 0.f;
    wx0 *= ((u32)x0 < 64u) ? 1.f : 0.f;
    wx1 *= ((u32)x1 < 64u) ? 1.f : 0.f;
    w00a[f] = wy0 * wx0; w01a[f] = wy0 * wx1;
    w10a[f] = wy1 * wx0; w11a[f] = wy1 * wx1;
    int y0c = min(63, max(0, y0)), y1c = min(63, max(0, y1));
    x0a[f] = min(63, max(0, x0));
    x1a[f] = min(63, max(0, x1));
    yw0a[f] = y0c - h + 4;                // in-window iff 0..8
    yw1a[f] = y1c - h + 4;
  };

  // issue all 16 ds_read corners for the current tap
  auto issue_lds = [&]() {
#pragma unroll
    for (int c = 0; c < 2; c++) {
      int slot = cp * 8 + c * 4 + lg;
#pragma unroll
      for (int f = 0; f < 2; f++) {
        int y0w = min(8, max(0, yw0a[f]));
        int y1w = min(8, max(0, yw1a[f]));
        int b0 = (y0w * 16 + slot) * 65;
        int b1 = (y1w * 16 + slot) * 65;
        q[c * 8 + f * 4 + 0] = ldsbuf[b0 + x0a[f]];
        q[c * 8 + f * 4 + 1] = ldsbuf[b0 + x1a[f]];
        q[c * 8 + f * 4 + 2] = ldsbuf[b1 + x0a[f]];
        q[c * 8 + f * 4 + 3] = ldsbuf[b1 + x1a[f]];
      }
    }
  };

  // rare out-of-window fallback: predicated loads straight from x (f32+pack)
  auto oow_fix = [&]() {
    bool bad = ((u32)yw0a[0] > 8u) | ((u32)yw1a[0] > 8u) |
               ((u32)yw0a[1] > 8u) | ((u32)yw1a[1] > 8u);
    if (__any(bad)) {
#pragma unroll
      for (int f = 0; f < 2; f++) {
        if ((u32)yw0a[f] > 8u) {
          int gy = (yw0a[f] + h - 4) * 64;
#pragma unroll
          for (int c = 0; c < 2; c++) {
            u32 r0[4], r1[4];
#pragma unroll
            for (int e = 0; e < 4; e++) {
              const float* pc = xsrc + (size_t)(cp * 64 + c * 32 + lg * 8 + 2 * e) * 4096 + gy;
              r0[e] = pack2(pc[x0a[f]], pc[4096 + x0a[f]]);
              r1[e] = pack2(pc[x1a[f]], pc[4096 + x1a[f]]);
            }
            uint4 v0, v1;
            v0.x = r0[0]; v0.y = r0[1]; v0.z = r0[2]; v0.w = r0[3];
            v1.x = r1[0]; v1.y = r1[1]; v1.z = r1[2]; v1.w = r1[3];
            q[c * 8 + f * 4 + 0] = v0;
            q[c * 8 + f * 4 + 1] = v1;
          }
        }
        if ((u32)yw1a[f] > 8u) {
          int gy = (yw1a[f] + h - 4) * 64;
#pragma unroll
          for (int c = 0; c < 2; c++) {
            u32 r0[4], r1[4];
#pragma unroll
            for (int e = 0; e < 4; e++) {
              const float* pc = xsrc + (size_t)(cp * 64 + c * 32 + lg * 8 + 2 * e) * 4096 + gy;
              r0[e] = pack2(pc[x0a[f]], pc[4096 + x0a[f]]);
              r1[e] = pack2(pc[x1a[f]], pc[4096 + x1a[f]]);
            }
            uint4 v0, v1;
            v0.x = r0[0]; v0.y = r0[1]; v0.z = r0[2]; v0.w = r0[3];
            v1.x = r1[0]; v1.y = r1[1]; v1.z = r1[2]; v1.w = r1[3];
            q[c * 8 + f * 4 + 2] = v0;
            q[c * 8 + f * 4 + 3] = v1;
          }
        }
      }
    }
  };

  // ---- prologue: tap 0 state + reads ----
  tapstate(0, 0, 0, dy0, dx0);
  tapstate(1, 0, 0, dy1, dx1);
  issue_lds();
  oow_fix();

#pragma unroll 1
  for (int tap = 0; tap < 9; tap++) {
    // ---- chunk c=0: consume wA ----
    {
      const u16* wpB = wbase + (size_t)(tap * 4 + 1) * 3072;
      wB0 = *(const uint4*)(wpB);        wB1 = *(const uint4*)(wpB + 512);
      wB2 = *(const uint4*)(wpB + 1024); wB3 = *(const uint4*)(wpB + 1536);
      wB4 = *(const uint4*)(wpB + 2048); wB5 = *(const uint4*)(wpB + 2560);

      uint4 a0 = blend4(q[0], q[1], q[2], q[3], w00a[0], w01a[0], w10a[0], w11a[0]);
      uint4 a1 = blend4(q[4], q[5], q[6], q[7], w00a[1], w01a[1], w10a[1], w11a[1]);
      bf16x8 af0 = as_bf(a0), af1 = as_bf(a1);
      __builtin_amdgcn_s_setprio(1);
      acc[0][0] = __builtin_amdgcn_mfma_f32_16x16x32_bf16(as_bf(wA0), af0, acc[0][0], 0, 0, 0);
      acc[1][0] = __builtin_amdgcn_mfma_f32_16x16x32_bf16(as_bf(wA1), af0, acc[1][0], 0, 0, 0);
      acc[2][0] = __builtin_amdgcn_mfma_f32_16x16x32_bf16(as_bf(wA2), af0, acc[2][0], 0, 0, 0);
      acc[3][0] = __builtin_amdgcn_mfma_f32_16x16x32_bf16(as_bf(wA3), af0, acc[3][0], 0, 0, 0);
      acc[4][0] = __builtin_amdgcn_mfma_f32_16x16x32_bf16(as_bf(wA4), af0, acc[4][0], 0, 0, 0);
      acc[5][0] = __builtin_amdgcn_mfma_f32_16x16x32_bf16(as_bf(wA5), af0, acc[5][0], 0, 0, 0);
      acc[0][1] = __builtin_amdgcn_mfma_f32_16x16x32_bf16(as_bf(wA0), af1, acc[0][1], 0, 0, 0);
      acc[1][1] = __builtin_amdgcn_mfma_f32_16x16x32_bf16(as_bf(wA1), af1, acc[1][1], 0, 0, 0);
      acc[2][1] = __builtin_amdgcn_mfma_f32_16x16x32_bf16(as_bf(wA2), af1, acc[2][1], 0, 0, 0);
      acc[3][1] = __builtin_amdgcn_mfma_f32_16x16x32_bf16(as_bf(wA3), af1, acc[3][1], 0, 0, 0);
      acc[4][1] = __builtin_amdgcn_mfma_f32_16x16x32_bf16(as_bf(wA4), af1, acc[4][1], 0, 0, 0);
      acc[5][1] = __builtin_amdgcn_mfma_f32_16x16x32_bf16(as_bf(wA5), af1, acc[5][1], 0, 0, 0);
      __builtin_amdgcn_s_setprio(0);
    }

    // ---- chunk c=1: consume wB ----
    {
      if (tap < 8) {
        const u16* wpA = wbase + (size_t)((tap + 1) * 4) * 3072;
        wA0 = *(const uint4*)(wpA);        wA1 = *(const uint4*)(wpA + 512);
        wA2 = *(const uint4*)(wpA + 1024); wA3 = *(const uint4*)(wpA + 1536);
        wA4 = *(const uint4*)(wpA + 2048); wA5 = *(const uint4*)(wpA + 2560);
      }

      uint4 a2 = blend4(q[8], q[9], q[10], q[11], w00a[0], w01a[0], w10a[0], w11a[0]);
      uint4 a3 = blend4(q[12], q[13], q[14], q[15], w00a[1], w01a[1], w10a[1], w11a[1]);

      // next tap: state + ds-issue (q now dead), dm prefetch 2 taps ahead
      if (tap < 8) {
        int tn = tap + 1;
        int ty = (tn * 11) >> 5;     // tn/3
        int tx = tn - ty * 3;
        tapstate(0, ty, tx, dyN[0], dxN[0]);
        tapstate(1, ty, tx, dyN[1], dxN[1]);
        issue_lds();
        oow_fix();
        if (tap < 7) {
          dyN[0] = dmb[(2 * tn + 2) * 4096];      dxN[0] = dmb[(2 * tn + 3) * 4096];
          dyN[1] = dmb[(2 * tn + 2) * 4096 + 16]; dxN[1] = dmb[(2 * tn + 3) * 4096 + 16];
        }
      }

      bf16x8 af2 = as_bf(a2), af3 = as_bf(a3);
      __builtin_amdgcn_s_setprio(1);
      acc[0][0] = __builtin_amdgcn_mfma_f32_16x16x32_bf16(as_bf(wB0), af2, acc[0][0], 0, 0, 0);
      acc[1][0] = __builtin_amdgcn_mfma_f32_16x16x32_bf16(as_bf(wB1), af2, acc[1][0], 0, 0, 0);
      acc[2][0] = __builtin_amdgcn_mfma_f32_16x16x32_bf16(as_bf(wB2), af2, acc[2][0], 0, 0, 0);
      acc[3][0] = __builtin_amdgcn_mfma_f32_16x16x32_bf16(as_bf(wB3), af2, acc[3][0], 0, 0, 0);
      acc[4][0] = __builtin_amdgcn_mfma_f32_16x16x32_bf16(as_bf(wB4), af2, acc[4][0], 0, 0, 0);
      acc[5][0] = __builtin_amdgcn_mfma_f32_16x16x32_bf16(as_bf(wB5), af2, acc[5][0], 0, 0, 0);
      acc[0][1] = __builtin_amdgcn_mfma_f32_16x16x32_bf16(as_bf(wB0), af3, acc[0][1], 0, 0, 0);
      acc[1][1] = __builtin_amdgcn_mfma_f32_16x16x32_bf16(as_bf(wB1), af3, acc[1][1], 0, 0, 0);
      acc[2][1] = __builtin_amdgcn_mfma_f32_16x16x32_bf16(as_bf(wB2), af3, acc[2][1], 0, 0, 0);
      acc[3][1] = __builtin_amdgcn_mfma_f32_16x16x32_bf16(as_bf(wB3), af3, acc[3][1], 0, 0, 0);
      acc[4][1] = __builtin_amdgcn_mfma_f32_16x16x32_bf16(as_bf(wB4), af3, acc[4][1], 0, 0, 0);
      acc[5][1] = __builtin_amdgcn_mfma_f32_16x16x32_bf16(as_bf(wB5), af3, acc[5][1], 0, 0, 0);
      __builtin_amdgcn_s_setprio(0);
    }
  }

  // ---- reduce the 4 K-partials per px-half (reuse staging LDS), store ----
  __syncthreads();                       // all LDS gather reads done
  const int rbase = pxh * 2304;          // uint4 units; 2*2304 = 4608 <= 9360
  if (sub > 0) {
#pragma unroll
    for (int nt = 0; nt < 6; nt++)
#pragma unroll
      for (int f = 0; f < 2; f++) {
        uint4 v;
        __builtin_memcpy(&v, &acc[nt][f], 16);
        ldsbuf[rbase + ((sub - 1) * 12 + nt * 2 + f) * 64 + lane] = v;
      }
  }
  __syncthreads();
  if (sub == 0) {
#pragma unroll
    for (int nt = 0; nt < 6; nt++)
#pragma unroll
      for (int f = 0; f < 2; f++) {
#pragma unroll
        for (int r = 0; r < 3; r++) {
          uint4 v = ldsbuf[rbase + (r * 12 + nt * 2 + f) * 64 + lane];
          f32x4 fv;
          __builtin_memcpy(&fv, &v, 16);
#pragma unroll
          for (int j = 0; j < 4; j++) acc[nt][f][j] += fv[j];
        }
      }
    float* op = out + ((size_t)b * 84 * 64 + h) * 64 + px0;
#pragma unroll
    for (int nt = 0; nt < 6; nt++)
#pragma unroll
      for (int j = 0; j < 4; j++) {
        int o = nt * 16 + lg * 4 + j;
        if (o < 84) {
          float bv = bias[o];
#pragma unroll
          for (int f = 0; f < 2; f++)
            op[(size_t)o * 4096 + f * 16 + lrow] = acc[nt][f][j] + bv;
        }
      }
  }
}

// ---- launch -----------------------------------------------------------------
extern "C" void kernel_launch(void* const* d_in, const int* in_sizes, int n_in,
                              void* d_out, int out_size, void* d_ws, size_t ws_size,
                              hipStream_t stream) {
  const float* x   = (const float*)d_in[0];
  const float* dm0 = (const float*)d_in[1];
  const float* dm1 = (const float*)d_in[2];
  const float* w0  = (const float*)d_in[3];
  const float* w1  = (const float*)d_in[4];
  const float* wf  = (const float*)d_in[5];
  const float* bf  = (const float*)d_in[6];
  float* out = (float*)d_out;

  u16* weffg = (u16*)d_ws;   // 432 KiB

  weff_k<<<144, 256, 0, stream>>>(w0, w1, wf, weffg);
  deform_main<<<512, 512, 0, stream>>>(x, weffg, dm0, dm1, bf, out);
}

// Round 17
// 61.914 us; speedup vs baseline: 1.3736x; 1.1279x over previous
//
#include <hip/hip_runtime.h>
#include <hip/hip_bf16.h>

using u16 = unsigned short;
using u32 = unsigned int;
typedef float f32x4 __attribute__((ext_vector_type(4)));
typedef float f32x2 __attribute__((ext_vector_type(2)));
typedef __bf16 bf16x8 __attribute__((ext_vector_type(8)));

// ---- helpers ----------------------------------------------------------------
static __device__ __forceinline__ float bflo(u32 u) { return __uint_as_float(u << 16); }
static __device__ __forceinline__ float bfhi(u32 u) { return __uint_as_float(u & 0xffff0000u); }

// RNE pack of two f32 -> bf16x2 (a in low half)
static __device__ __forceinline__ u32 pack2(float a, float b) {
  __hip_bfloat16 ha = __float2bfloat16(a);
  __hip_bfloat16 hb = __float2bfloat16(b);
  u16 ra, rb;
  __builtin_memcpy(&ra, &ha, 2);
  __builtin_memcpy(&rb, &hb, 2);
  return (u32)ra | ((u32)rb << 16);
}

static __device__ __forceinline__ u16 f2bf(float f) {
  u32 u = __float_as_uint(f);
  u32 r = (u + 0x7fffu + ((u >> 16) & 1u)) >> 16;
  return (u16)r;
}

static __device__ __forceinline__ bf16x8 as_bf(uint4 v) {
  bf16x8 r;
  __builtin_memcpy(&r, &v, 16);
  return r;
}

// truncating pack of two blended f32 -> bf16x2, single v_perm_b32
static __device__ __forceinline__ u32 packtrunc(float lo, float hi) {
  return __builtin_amdgcn_perm(__float_as_uint(hi), __float_as_uint(lo), 0x07060302u);
}

static __device__ __forceinline__ f32x2 unpk(u32 u) {
  f32x2 r;
  r.x = bflo(u);
  r.y = bfhi(u);
  return r;
}

// 4-corner bilinear blend of 8 bf16 channels -> bf16x8 fragment (as uint4)
static __device__ __forceinline__ uint4 blend4(uint4 a, uint4 b, uint4 c, uint4 d,
                                               float w00, float w01, float w10, float w11) {
  uint4 r;
#pragma unroll
  for (int j = 0; j < 4; j++) {
    f32x2 v = unpk((&a.x)[j]) * w00;
    v += unpk((&b.x)[j]) * w01;
    v += unpk((&c.x)[j]) * w10;
    v += unpk((&d.x)[j]) * w11;
    (&r.x)[j] = packtrunc(v.x, v.y);
  }
  return r;
}

// ---- kernel 1: combined prep = transpose (blocks 0-511) + weff (512-655) ----
// One launch, independent work, phases overlap across CUs.
// Transpose: x [B,C,H,W] f32 -> xT [B,H,W,C] bf16, float4 loads (r11 version).
// weff: fully-LDS inner loop (r16 lesson: 504 per-thread global wf loads made
// weff_k ~10us; staging wfs[84][84] makes the loop pure broadcast/conflict-free
// LDS). Output element idx = ((ks*6+nt)*64+lg*16+lrow)*8+j, n=nt*16+lrow,
// kc=lg*8+j (unchanged fragment layout).
__global__ __launch_bounds__(256) void prep_k(const float* __restrict__ x,
                                              u16* __restrict__ xT,
                                              const float* __restrict__ w0,
                                              const float* __restrict__ w1,
                                              const float* __restrict__ wf,
                                              u16* __restrict__ weffg) {
  __shared__ float ws[84][32];    // w-slice [oc][kc]
  __shared__ float wfs[84][84];   // wf-slice [n][oc]
  const int blk = blockIdx.x;
  const int t = threadIdx.x;

  if (blk < 512) {
    // ---- transpose part ----
    const int b = blk >> 6, y = blk & 63;
    const int cg = t >> 4;
    const int w4 = (t & 15) * 4;
    const float* xp = x + ((size_t)(b * 128) * 64 + y) * 64;
    u16* op = xT + ((size_t)(b * 64 + y) * 64) * 128;
    float4 v[8];
#pragma unroll
    for (int k = 0; k < 8; k++)
      v[k] = *(const float4*)(xp + (size_t)(cg * 8 + k) * 4096 + w4);
#pragma unroll
    for (int ww = 0; ww < 4; ww++) {
      u32 rr[4];
#pragma unroll
      for (int p = 0; p < 4; p++)
        rr[p] = pack2(((const float*)&v[2 * p])[ww], ((const float*)&v[2 * p + 1])[ww]);
      uint4 r;
      r.x = rr[0]; r.y = rr[1]; r.z = rr[2]; r.w = rr[3];
      *(uint4*)(op + (size_t)(w4 + ww) * 128 + cg * 8) = r;
    }
    return;
  }

  // ---- weff part ----
  const int wblk = blk - 512;        // 0..143
  const int ks = wblk >> 1, nh = wblk & 1;
  const int br = ks >= 36 ? 1 : 0;
  const int ksb = ks - br * 36;
  const int tap = ksb >> 2, chunk = ksb & 3;
  const float* w = br ? w1 : w0;
  for (int i = t; i < 2688; i += 256) {
    int oc = i >> 5, kc = i & 31;
    ws[oc][kc] = w[oc * 1152 + (chunk * 32 + kc) * 9 + tap];
  }
  for (int i = t; i < 7056; i += 256) {
    int n = i / 84, oc = i - n * 84;
    wfs[n][oc] = wf[n * 168 + br * 84 + oc];
  }
  __syncthreads();

  const int kc = t & 31, ng = t >> 5;   // ng 0..7
  const int n0 = nh * 48 + ng * 6;
  int nc[6];
  bool nv[6];
#pragma unroll
  for (int i = 0; i < 6; i++) {
    int n = n0 + i;
    nv[i] = n < 84;
    nc[i] = min(n, 83);
  }
  float accv[6] = {0.f, 0.f, 0.f, 0.f, 0.f, 0.f};
#pragma unroll 4
  for (int oc = 0; oc < 84; oc++) {
    float wv_ = ws[oc][kc];
#pragma unroll
    for (int i = 0; i < 6; i++) accv[i] += wfs[nc[i]][oc] * wv_;
  }
#pragma unroll
  for (int i = 0; i < 6; i++) {
    int n = n0 + i;
    int nt = n >> 4, lrow = n & 15, lg = kc >> 3, j = kc & 7;
    int idx = ((ks * 6 + nt) * 64 + lg * 16 + lrow) * 8 + j;
    weffg[idx] = f2bf(nv[i] ? accv[i] : 0.f);
  }
}

// ---- kernel 2: LDS-resident row-window deform-sample + GEMM (r10 verbatim) --
// 512 blocks = (b:8 -> XCD) x (h:64), 512 threads (8 waves).
// Wave wv: pxh = wv>>2 (32-px half), br = (wv>>1)&1, cp = wv&1 (K quarter).
// Best measured core: 50.3us (r10). Left byte-identical.
__global__ __launch_bounds__(512, 1) void deform_main(
    const u16* __restrict__ xT, const u16* __restrict__ weffg,
    const float* __restrict__ dm0, const float* __restrict__ dm1,
    const float* __restrict__ bias, float* __restrict__ out) {
  __shared__ uint4 ldsbuf[9360];   // 9 rows * 16 slots * 65 * 16B = 146.25 KiB

  const int t = threadIdx.x;
  const int wv = t >> 6, lane = t & 63;
  const int pxh = wv >> 2, br = (wv >> 1) & 1, cp = wv & 1;
  const int lrow = lane & 15, lg = lane >> 4;
  const int blk = blockIdx.x;
  const int b = blk & 7, h = blk >> 3;
  const int px0 = pxh * 32;

  const u16* xb = xT + (size_t)b * 524288;

  // ---- stage rows [h-4, h+4] into LDS (coalesced 16B, 18 iters/thread) ----
#pragma unroll
  for (int k = 0; k < 18; k++) {
    int u = t + (k << 9);          // < 9216
    int i = u >> 10;               // window row 0..8
    int ul = u & 1023;             // x*16 + slot
    int ysr = min(63, max(0, h - 4 + i));
    uint4 v = *(const uint4*)(xb + ysr * 8192 + ul * 8);
    int s = ul & 15, xx = ul >> 4;
    ldsbuf[(i * 16 + s) * 65 + xx] = v;
  }
  __syncthreads();

  const float* dmb = (br ? dm1 : dm0) + (size_t)b * 73728 + h * 64 + px0 + lrow;
  const u16* wbase = weffg + (size_t)(br * 36 + cp * 2) * 3072 + lane * 8;

  f32x4 acc[6][2];
#pragma unroll
  for (int i = 0; i < 6; i++)
#pragma unroll
    for (int f = 0; f < 2; f++) acc[i][f] = f32x4{0.f, 0.f, 0.f, 0.f};

  float w00a[2], w01a[2], w10a[2], w11a[2];
  int x0a[2], x1a[2], yw0a[2], yw1a[2];   // yw*: window-relative rows (may be OOW)
  float dyN[2], dxN[2];
  uint4 q[16];                            // [c][f][corner] in flight (1 tap ahead)
  uint4 wA0, wA1, wA2, wA3, wA4, wA5;     // weff ping
  uint4 wB0, wB1, wB2, wB3, wB4, wB5;     // weff pong

  auto tapstate = [&](int f, int ty, int tx, float dy, float dx) {
    float pyf = (float)(h + ty - 1) + dy;
    float pxf = (float)(px0 + f * 16 + lrow + tx - 1) + dx;
    float y0f = floorf(pyf), x0f = floorf(pxf);
    int y0 = (int)y0f, x0 = (int)x0f;
    float wy1 = pyf - y0f, wx1 = pxf - x0f;
    float wy0 = 1.f - wy1, wx0 = 1.f - wx1;
    int y1 = y0 + 1, x1 = x0 + 1;
    wy0 *= ((u32)y0 < 64u) ? 1.f : 0.f;
    wy1 *= ((u32)y1 < 64u) ? 1.f : 0.f;
    wx0 *= ((u32)x0 < 64u) ? 1.f : 0.f;
    wx1 *= ((u32)x1 < 64u) ? 1.f : 0.f;
    w00a[f] = wy0 * wx0; w01a[f] = wy0 * wx1;
    w10a[f] = wy1 * wx0; w11a[f] = wy1 * wx1;
    int y0c = min(63, max(0, y0)), y1c = min(63, max(0, y1));
    x0a[f] = min(63, max(0, x0));
    x1a[f] = min(63, max(0, x1));
    yw0a[f] = y0c - h + 4;                // in-window iff 0..8
    yw1a[f] = y1c - h + 4;
  };

  // issue all 16 ds_read corners for the current tap
  auto issue_lds = [&]() {
#pragma unroll
    for (int c = 0; c < 2; c++) {
      int slot = cp * 8 + c * 4 + lg;
#pragma unroll
      for (int f = 0; f < 2; f++) {
        int y0w = min(8, max(0, yw0a[f]));
        int y1w = min(8, max(0, yw1a[f]));
        int b0 = (y0w * 16 + slot) * 65;
        int b1 = (y1w * 16 + slot) * 65;
        q[c * 8 + f * 4 + 0] = ldsbuf[b0 + x0a[f]];
        q[c * 8 + f * 4 + 1] = ldsbuf[b0 + x1a[f]];
        q[c * 8 + f * 4 + 2] = ldsbuf[b1 + x0a[f]];
        q[c * 8 + f * 4 + 3] = ldsbuf[b1 + x1a[f]];
      }
    }
  };

  // rare out-of-window fallback: predicated global corner loads
  auto oow_fix = [&]() {
    bool bad = ((u32)yw0a[0] > 8u) | ((u32)yw1a[0] > 8u) |
               ((u32)yw0a[1] > 8u) | ((u32)yw1a[1] > 8u);
    if (__any(bad)) {
#pragma unroll
      for (int f = 0; f < 2; f++) {
        if ((u32)yw0a[f] > 8u) {
          const u16* p = xb + (yw0a[f] + h - 4) * 8192 + cp * 64 + lg * 8;
#pragma unroll
          for (int c = 0; c < 2; c++) {
            q[c * 8 + f * 4 + 0] = *(const uint4*)(p + c * 32 + x0a[f] * 128);
            q[c * 8 + f * 4 + 1] = *(const uint4*)(p + c * 32 + x1a[f] * 128);
          }
        }
        if ((u32)yw1a[f] > 8u) {
          const u16* p = xb + (yw1a[f] + h - 4) * 8192 + cp * 64 + lg * 8;
#pragma unroll
          for (int c = 0; c < 2; c++) {
            q[c * 8 + f * 4 + 2] = *(const uint4*)(p + c * 32 + x0a[f] * 128);
            q[c * 8 + f * 4 + 3] = *(const uint4*)(p + c * 32 + x1a[f] * 128);
          }
        }
      }
    }
  };

  // ---- prologue: tap 0 state + reads, dm(tap1), weff step0 ----
  {
    float dy0 = dmb[0], dx0 = dmb[4096];
    float dy1 = dmb[16], dx1 = dmb[4096 + 16];
    tapstate(0, 0, 0, dy0, dx0);
    tapstate(1, 0, 0, dy1, dx1);
  }
  issue_lds();
  oow_fix();
  dyN[0] = dmb[2 * 4096];      dxN[0] = dmb[3 * 4096];
  dyN[1] = dmb[2 * 4096 + 16]; dxN[1] = dmb[3 * 4096 + 16];
  {
    const u16* wp = wbase;   // (tap0, c0)
    wA0 = *(const uint4*)(wp);        wA1 = *(const uint4*)(wp + 512);
    wA2 = *(const uint4*)(wp + 1024); wA3 = *(const uint4*)(wp + 1536);
    wA4 = *(const uint4*)(wp + 2048); wA5 = *(const uint4*)(wp + 2560);
  }

#pragma unroll 1
  for (int tap = 0; tap < 9; tap++) {
    // ---- chunk c=0: consume wA ----
    {
      const u16* wpB = wbase + (size_t)(tap * 4 + 1) * 3072;
      wB0 = *(const uint4*)(wpB);        wB1 = *(const uint4*)(wpB + 512);
      wB2 = *(const uint4*)(wpB + 1024); wB3 = *(const uint4*)(wpB + 1536);
      wB4 = *(const uint4*)(wpB + 2048); wB5 = *(const uint4*)(wpB + 2560);

      uint4 a0 = blend4(q[0], q[1], q[2], q[3], w00a[0], w01a[0], w10a[0], w11a[0]);
      uint4 a1 = blend4(q[4], q[5], q[6], q[7], w00a[1], w01a[1], w10a[1], w11a[1]);
      bf16x8 af0 = as_bf(a0), af1 = as_bf(a1);
      __builtin_amdgcn_s_setprio(1);
      acc[0][0] = __builtin_amdgcn_mfma_f32_16x16x32_bf16(as_bf(wA0), af0, acc[0][0], 0, 0, 0);
      acc[1][0] = __builtin_amdgcn_mfma_f32_16x16x32_bf16(as_bf(wA1), af0, acc[1][0], 0, 0, 0);
      acc[2][0] = __builtin_amdgcn_mfma_f32_16x16x32_bf16(as_bf(wA2), af0, acc[2][0], 0, 0, 0);
      acc[3][0] = __builtin_amdgcn_mfma_f32_16x16x32_bf16(as_bf(wA3), af0, acc[3][0], 0, 0, 0);
      acc[4][0] = __builtin_amdgcn_mfma_f32_16x16x32_bf16(as_bf(wA4), af0, acc[4][0], 0, 0, 0);
      acc[5][0] = __builtin_amdgcn_mfma_f32_16x16x32_bf16(as_bf(wA5), af0, acc[5][0], 0, 0, 0);
      acc[0][1] = __builtin_amdgcn_mfma_f32_16x16x32_bf16(as_bf(wA0), af1, acc[0][1], 0, 0, 0);
      acc[1][1] = __builtin_amdgcn_mfma_f32_16x16x32_bf16(as_bf(wA1), af1, acc[1][1], 0, 0, 0);
      acc[2][1] = __builtin_amdgcn_mfma_f32_16x16x32_bf16(as_bf(wA2), af1, acc[2][1], 0, 0, 0);
      acc[3][1] = __builtin_amdgcn_mfma_f32_16x16x32_bf16(as_bf(wA3), af1, acc[3][1], 0, 0, 0);
      acc[4][1] = __builtin_amdgcn_mfma_f32_16x16x32_bf16(as_bf(wA4), af1, acc[4][1], 0, 0, 0);
      acc[5][1] = __builtin_amdgcn_mfma_f32_16x16x32_bf16(as_bf(wA5), af1, acc[5][1], 0, 0, 0);
      __builtin_amdgcn_s_setprio(0);
    }

    // ---- chunk c=1: consume wB ----
    {
      if (tap < 8) {
        const u16* wpA = wbase + (size_t)((tap + 1) * 4) * 3072;
        wA0 = *(const uint4*)(wpA);        wA1 = *(const uint4*)(wpA + 512);
        wA2 = *(const uint4*)(wpA + 1024); wA3 = *(const uint4*)(wpA + 1536);
        wA4 = *(const uint4*)(wpA + 2048); wA5 = *(const uint4*)(wpA + 2560);
      }

      uint4 a2 = blend4(q[8], q[9], q[10], q[11], w00a[0], w01a[0], w10a[0], w11a[0]);
      uint4 a3 = blend4(q[12], q[13], q[14], q[15], w00a[1], w01a[1], w10a[1], w11a[1]);

      // next tap: state + ds-issue (q now dead), dm prefetch 2 taps ahead
      if (tap < 8) {
        int tn = tap + 1;
        int ty = (tn * 11) >> 5;     // tn/3
        int tx = tn - ty * 3;
        tapstate(0, ty, tx, dyN[0], dxN[0]);
        tapstate(1, ty, tx, dyN[1], dxN[1]);
        issue_lds();
        oow_fix();
        if (tap < 7) {
          dyN[0] = dmb[(2 * tn + 2) * 4096];      dxN[0] = dmb[(2 * tn + 3) * 4096];
          dyN[1] = dmb[(2 * tn + 2) * 4096 + 16]; dxN[1] = dmb[(2 * tn + 3) * 4096 + 16];
        }
      }

      bf16x8 af2 = as_bf(a2), af3 = as_bf(a3);
      __builtin_amdgcn_s_setprio(1);
      acc[0][0] = __builtin_amdgcn_mfma_f32_16x16x32_bf16(as_bf(wB0), af2, acc[0][0], 0, 0, 0);
      acc[1][0] = __builtin_amdgcn_mfma_f32_16x16x32_bf16(as_bf(wB1), af2, acc[1][0], 0, 0, 0);
      acc[2][0] = __builtin_amdgcn_mfma_f32_16x16x32_bf16(as_bf(wB2), af2, acc[2][0], 0, 0, 0);
      acc[3][0] = __builtin_amdgcn_mfma_f32_16x16x32_bf16(as_bf(wB3), af2, acc[3][0], 0, 0, 0);
      acc[4][0] = __builtin_amdgcn_mfma_f32_16x16x32_bf16(as_bf(wB4), af2, acc[4][0], 0, 0, 0);
      acc[5][0] = __builtin_amdgcn_mfma_f32_16x16x32_bf16(as_bf(wB5), af2, acc[5][0], 0, 0, 0);
      acc[0][1] = __builtin_amdgcn_mfma_f32_16x16x32_bf16(as_bf(wB0), af3, acc[0][1], 0, 0, 0);
      acc[1][1] = __builtin_amdgcn_mfma_f32_16x16x32_bf16(as_bf(wB1), af3, acc[1][1], 0, 0, 0);
      acc[2][1] = __builtin_amdgcn_mfma_f32_16x16x32_bf16(as_bf(wB2), af3, acc[2][1], 0, 0, 0);
      acc[3][1] = __builtin_amdgcn_mfma_f32_16x16x32_bf16(as_bf(wB3), af3, acc[3][1], 0, 0, 0);
      acc[4][1] = __builtin_amdgcn_mfma_f32_16x16x32_bf16(as_bf(wB4), af3, acc[4][1], 0, 0, 0);
      acc[5][1] = __builtin_amdgcn_mfma_f32_16x16x32_bf16(as_bf(wB5), af3, acc[5][1], 0, 0, 0);
      __builtin_amdgcn_s_setprio(0);
    }
  }

  // ---- reduce the 4 K-partials per px-half (reuse staging LDS), store ----
  __syncthreads();                       // all LDS gather reads done
  const int sub = wv & 3;                // br*2+cp
  const int rbase = pxh * 2304;          // uint4 units; 2*2304 = 4608 <= 9360
  if (sub > 0) {
#pragma unroll
    for (int nt = 0; nt < 6; nt++)
#pragma unroll
      for (int f = 0; f < 2; f++) {
        uint4 v;
        __builtin_memcpy(&v, &acc[nt][f], 16);
        ldsbuf[rbase + ((sub - 1) * 12 + nt * 2 + f) * 64 + lane] = v;
      }
  }
  __syncthreads();
  if (sub == 0) {
#pragma unroll
    for (int nt = 0; nt < 6; nt++)
#pragma unroll
      for (int f = 0; f < 2; f++) {
#pragma unroll
        for (int r = 0; r < 3; r++) {
          uint4 v = ldsbuf[rbase + (r * 12 + nt * 2 + f) * 64 + lane];
          f32x4 fv;
          __builtin_memcpy(&fv, &v, 16);
#pragma unroll
          for (int j = 0; j < 4; j++) acc[nt][f][j] += fv[j];
        }
      }
    float* op = out + ((size_t)b * 84 * 64 + h) * 64 + px0;
#pragma unroll
    for (int nt = 0; nt < 6; nt++)
#pragma unroll
      for (int j = 0; j < 4; j++) {
        int o = nt * 16 + lg * 4 + j;
        if (o < 84) {
          float bv = bias[o];
#pragma unroll
          for (int f = 0; f < 2; f++)
            op[(size_t)o * 4096 + f * 16 + lrow] = acc[nt][f][j] + bv;
        }
      }
  }
}

// ---- launch -----------------------------------------------------------------
extern "C" void kernel_launch(void* const* d_in, const int* in_sizes, int n_in,
                              void* d_out, int out_size, void* d_ws, size_t ws_size,
                              hipStream_t stream) {
  const float* x   = (const float*)d_in[0];
  const float* dm0 = (const float*)d_in[1];
  const float* dm1 = (const float*)d_in[2];
  const float* w0  = (const float*)d_in[3];
  const float* w1  = (const float*)d_in[4];
  const float* wf  = (const float*)d_in[5];
  const float* bf  = (const float*)d_in[6];
  float* out = (float*)d_out;

  u16* xT = (u16*)d_ws;                                               // 8 MiB
  u16* weffg = (u16*)((char*)d_ws + (size_t)8 * 64 * 64 * 128 * 2);   // 432 KiB

  prep_k<<<656, 256, 0, stream>>>(x, xT, w0, w1, wf, weffg);
  deform_main<<<512, 512, 0, stream>>>(xT, weffg, dm0, dm1, bf, out);
}